// Round 9
// baseline (729.183 us; speedup 1.0000x reference)
//
#include <hip/hip_runtime.h>

// Problem: B=8, C=256, H=W=160. n = B*C = 2048 planes.
// Per plane: l[h]=x[h,:]·fcw_w ; alpha=softmax_h(l) ; row[w]=sum_h alpha[h]x[h,w]
//            beta=softmax_w(row*sum(fch_w)) ; s=sum_w beta[w]row[w] ; out[:,:]=s
// Biases are softmax-shift-invariant -> ignored.
//
// v9: FUSED last-block-merge. v8 evidence: part(~45-50us reads) then
// bcast(~33us writes) are serialized by dispatch order; neither stream
// alone sustains 6.3 TB/s, but interleaved they can fill each other's
// bubbles (420 MB / 6.3 TB/s = 67us ideal vs ~80+gap serialized).
// Structure: 2 blocks per plane compute half-plane softmax partials
// {rowacc[160], m, Z} -> ws (plain stores); __threadfence + device-scope
// atomicAdd(cnt[n]); the SECOND-arriving block acquires, merges (exact
// flash-style), computes s, and nt-broadcast-stores the whole plane.
// Merge events are spread through the dispatch -> chip-wide read/write
// overlap. Counters zeroed per launch via 8 KB hipMemsetAsync
// (graph-capture-safe; harness reset uses hipMemsetAsync itself).
// Fallback to v7 two-kernel path if ws too small.

#define HH 160
#define WW 160
#define NPLANE (HH * WW)
#define BLOCK 320
#define QN 40     // float4 columns per row
#define PSTR 41   // pad: conflict-light LDS partial gather

// -- split geometry --
#define HALF 80   // rows per partial block
#define RPTH 10   // rows per v-group (HALF / 8)
#define WSSTR 164 // floats per ws record: rowacc[160], m, Z, pad2
#define NPL 2048  // planes

typedef float f32x4 __attribute__((ext_vector_type(4)));

// ============ v9 fused: half-plane partial + last-block merge/store =======
__global__ void __launch_bounds__(BLOCK, 7) sa1_fused(
    const float* __restrict__ x,
    const float* __restrict__ fcw_w,
    const float* __restrict__ fch_w,
    unsigned int* __restrict__ cnt,
    float* __restrict__ ws,
    float* __restrict__ out)
{
    const int bid = blockIdx.x;
    const int n = bid >> 1;
    const int g = bid & 1;
    const int t = threadIdx.x;
    const int q = t % QN;
    const int v = t / QN;

    __shared__ float pbuf[HALF * PSTR];  // dot partials; later row partials [8][160]
    __shared__ float larr[HALF];         // l[h] for my 80 rows
    __shared__ float sc[4];              // m_part, Z_part, S, s
    __shared__ int lastf;

    const float* xp = x + (size_t)n * NPLANE + (size_t)g * HALF * WW;

    const float4 ww = *(const float4*)(fcw_w + 4 * q);

    // ---- P1: load my 10 float4 (coalesced nt) + dot partials ----
    f32x4 xr[RPTH];
#pragma unroll
    for (int r = 0; r < RPTH; ++r)
        xr[r] = __builtin_nontemporal_load(
            (const f32x4*)(xp + (size_t)(v * RPTH + r) * WW + 4 * q));
#pragma unroll
    for (int r = 0; r < RPTH; ++r) {
        float p = xr[r].x * ww.x + xr[r].y * ww.y + xr[r].z * ww.z + xr[r].w * ww.w;
        pbuf[(v * RPTH + r) * PSTR + q] = p;
    }
    __syncthreads();  // B1

    // ---- P2: l[h], 4 threads per row (80 rows x 4 segs of 10) + 4-lane shfl ----
    {
        const int row = t >> 2;          // [0,80)
        const int seg = t & 3;           // [0,4)
        const float* pr = pbuf + row * PSTR + seg * 10;
        float s0 = 0.f, s1 = 0.f;
#pragma unroll
        for (int i = 0; i < 10; i += 2) { s0 += pr[i]; s1 += pr[i + 1]; }
        float hs = s0 + s1;
        hs += __shfl_xor(hs, 1, 64);
        hs += __shfl_xor(hs, 2, 64);
        if (seg == 0) larr[row] = hs;
    }
    __syncthreads();  // B2

    // ---- P3: wave0: m_part, Z_part over 80 logits; wave1: S = sum(fch_w) ----
    if (t < 32) {
        const float l0 = larr[t];
        const float l1 = larr[t + 32];
        const float l2 = (t < 16) ? larr[t + 64] : -3.0e38f;
        float m = fmaxf(l0, fmaxf(l1, l2));
#pragma unroll
        for (int off = 16; off >= 1; off >>= 1)
            m = fmaxf(m, __shfl_down(m, off, 32));
        m = __shfl(m, 0, 32);
        float z = __expf(l0 - m) + __expf(l1 - m) + __expf(l2 - m);
#pragma unroll
        for (int off = 16; off >= 1; off >>= 1)
            z += __shfl_down(z, off, 32);
        if (t == 0) { sc[0] = m; sc[1] = z; }
    } else if (t >= 64 && t < 96) {
        const int u = t - 64;
        float s = 0.f;
#pragma unroll
        for (int j = 0; j < 5; ++j) s += fch_w[u + 32 * j];
#pragma unroll
        for (int off = 16; off >= 1; off >>= 1)
            s += __shfl_down(s, off, 32);
        if (u == 0) sc[2] = s;
    }
    __syncthreads();  // B3

    // ---- P4: weighted row partials, exp inline (x still in registers) ----
    const float m = sc[0];
    float4 rp = make_float4(0.f, 0.f, 0.f, 0.f);
#pragma unroll
    for (int r = 0; r < RPTH; ++r) {
        const float a = __expf(larr[v * RPTH + r] - m);  // LDS broadcast
        rp.x += a * xr[r].x; rp.y += a * xr[r].y;
        rp.z += a * xr[r].z; rp.w += a * xr[r].w;
    }
    // pbuf dead since B2; write row partials [8][160]
    *(float4*)(pbuf + v * WW + 4 * q) = rp;
    __syncthreads();  // B4

    // ---- P5: emit ws record {rowacc[160], m, Z} (PLAIN stores: published) ----
    float* wsr = ws + (size_t)bid * WSSTR;
    if (t < WW) {
        float rs = 0.f;
#pragma unroll
        for (int vv = 0; vv < 8; ++vv) rs += pbuf[vv * WW + t];  // bank=t%32: clean
        wsr[t] = rs;                     // unnormalized; merge handles Z
    }
    if (t == 0) { wsr[160] = sc[0]; wsr[161] = sc[1]; }
    __syncthreads();  // B5: all ws writes issued before the fence

    // ---- P6: publish + elect merger (device-scope; cross-XCD safe) ----
    if (t == 0) {
        __threadfence();  // release this block's ws record
        unsigned int old = __hip_atomic_fetch_add(
            &cnt[n], 1u, __ATOMIC_ACQ_REL, __HIP_MEMORY_SCOPE_AGENT);
        lastf = (old == 1);
    }
    __syncthreads();  // B6: broadcasts lastf; orders remote reads after acquire
    if (!lastf) return;

    // ---- P7 (merger only): wave0 merges 2 partials -> s ----
    const float* r0 = ws + (size_t)(2 * n) * WSSTR;
    const float* r1 = r0 + WSSTR;
    if (t < 32) {
        const float m0 = r0[160], z0 = r0[161];
        const float m1 = r1[160], z1 = r1[161];
        const float mm = fmaxf(m0, m1);
        const float f0 = __expf(m0 - mm);
        const float f1 = __expf(m1 - mm);
        const float rcpZ = 1.0f / (f0 * z0 + f1 * z1);
        const float S = sc[2];
        float rv[5], bl[5];
#pragma unroll
        for (int j = 0; j < 5; ++j) {
            const int w = t + 32 * j;
            rv[j] = (f0 * r0[w] + f1 * r1[w]) * rcpZ;  // row[w]
            bl[j] = rv[j] * S;
        }
        float mb = bl[0];
#pragma unroll
        for (int j = 1; j < 5; ++j) mb = fmaxf(mb, bl[j]);
#pragma unroll
        for (int off = 16; off >= 1; off >>= 1)
            mb = fmaxf(mb, __shfl_down(mb, off, 32));
        mb = __shfl(mb, 0, 32);
        float zb = 0.f, sd = 0.f;
#pragma unroll
        for (int j = 0; j < 5; ++j) {
            float e = __expf(bl[j] - mb);
            zb += e; sd += e * rv[j];
        }
#pragma unroll
        for (int off = 16; off >= 1; off >>= 1) {
            zb += __shfl_down(zb, off, 32);
            sd += __shfl_down(sd, off, 32);
        }
        if (t == 0) sc[3] = sd / zb;
    }
    __syncthreads();  // B7

    // ---- P8 (merger only): nt broadcast-store the WHOLE plane ----
    const float sv = sc[3];
    const f32x4 o = { sv, sv, sv, sv };
    float* op = out + (size_t)n * NPLANE;
#pragma unroll
    for (int i = 0; i < 20; ++i)
        __builtin_nontemporal_store(
            o, (f32x4*)(op + 4 * (size_t)(i * BLOCK + t)));
}

// ================= fallback (v7 path) if workspace is too small ===========
#define RPT 20
#define BBLK 256
#define BIT (NPLANE / 4 / BBLK)

__global__ void __launch_bounds__(BLOCK, 4) sa1_reduce(
    const float* __restrict__ x,
    const float* __restrict__ fcw_w,
    const float* __restrict__ fch_w,
    float* __restrict__ s_out)
{
    const int n = blockIdx.x;
    const int t = threadIdx.x;
    const int q = t % QN;
    const int v = t / QN;

    __shared__ float pbuf[HH * PSTR];
    __shared__ float larrA[HH];
    __shared__ float larrB[HH];
    __shared__ float sc[4];

    const float* xp = x + (size_t)n * NPLANE;
    const float4 ww = *(const float4*)(fcw_w + 4 * q);

    f32x4 xr[RPT];
#pragma unroll
    for (int r = 0; r < RPT; ++r)
        xr[r] = __builtin_nontemporal_load(
            (const f32x4*)(xp + (size_t)(v * RPT + r) * WW + 4 * q));
#pragma unroll
    for (int r = 0; r < RPT; ++r) {
        float p = xr[r].x * ww.x + xr[r].y * ww.y + xr[r].z * ww.z + xr[r].w * ww.w;
        pbuf[(v * RPT + r) * PSTR + q] = p;
    }
    __syncthreads();

    {
        const int h = (t < HH) ? t : (t - HH);
        const int qb = (t < HH) ? 0 : (QN / 2);
        const float* pr = pbuf + h * PSTR + qb;
        float s0 = 0.f, s1 = 0.f, s2 = 0.f, s3 = 0.f;
#pragma unroll
        for (int qq = 0; qq < QN / 2; qq += 4) {
            s0 += pr[qq]; s1 += pr[qq + 1]; s2 += pr[qq + 2]; s3 += pr[qq + 3];
        }
        float hs = (s0 + s1) + (s2 + s3);
        if (t < HH) larrA[h] = hs; else larrB[h] = hs;
    }
    __syncthreads();

    if (t < 32) {
        float lv[5];
#pragma unroll
        for (int j = 0; j < 5; ++j) lv[j] = larrA[t + 32 * j] + larrB[t + 32 * j];
        float m = lv[0];
#pragma unroll
        for (int j = 1; j < 5; ++j) m = fmaxf(m, lv[j]);
#pragma unroll
        for (int off = 16; off >= 1; off >>= 1)
            m = fmaxf(m, __shfl_down(m, off, 32));
        m = __shfl(m, 0, 32);
        float z = 0.f;
#pragma unroll
        for (int j = 0; j < 5; ++j) z += __expf(lv[j] - m);
#pragma unroll
        for (int off = 16; off >= 1; off >>= 1)
            z += __shfl_down(z, off, 32);
        if (t == 0) { sc[0] = m; sc[1] = z; }
    } else if (t >= 64 && t < 96) {
        const int u = t - 64;
        float s = 0.f;
#pragma unroll
        for (int j = 0; j < 5; ++j) s += fch_w[u + 32 * j];
#pragma unroll
        for (int off = 16; off >= 1; off >>= 1)
            s += __shfl_down(s, off, 32);
        if (u == 0) sc[2] = s;
    }
    __syncthreads();

    const float m = sc[0];
    float4 rp = make_float4(0.f, 0.f, 0.f, 0.f);
#pragma unroll
    for (int r = 0; r < RPT; ++r) {
        const int h = v * RPT + r;
        const float a = __expf((larrA[h] + larrB[h]) - m);
        rp.x += a * xr[r].x; rp.y += a * xr[r].y;
        rp.z += a * xr[r].z; rp.w += a * xr[r].w;
    }
    *(float4*)(pbuf + v * WW + 4 * q) = rp;
    __syncthreads();

    if (t < 32) {
        const float S = sc[2];
        const float rcpZ = 1.0f / sc[1];
        float rv[5], bl[5];
#pragma unroll
        for (int j = 0; j < 5; ++j) {
            const int w = t + 32 * j;
            float rs = 0.f;
#pragma unroll
            for (int vv = 0; vv < 8; ++vv) rs += pbuf[vv * WW + w];
            rv[j] = rs * rcpZ;
            bl[j] = rv[j] * S;
        }
        float mb = bl[0];
#pragma unroll
        for (int j = 1; j < 5; ++j) mb = fmaxf(mb, bl[j]);
#pragma unroll
        for (int off = 16; off >= 1; off >>= 1)
            mb = fmaxf(mb, __shfl_down(mb, off, 32));
        mb = __shfl(mb, 0, 32);
        float zb = 0.f, sd = 0.f;
#pragma unroll
        for (int j = 0; j < 5; ++j) {
            float e = __expf(bl[j] - mb);
            zb += e; sd += e * rv[j];
        }
#pragma unroll
        for (int off = 16; off >= 1; off >>= 1) {
            zb += __shfl_down(zb, off, 32);
            sd += __shfl_down(sd, off, 32);
        }
        if (t == 0) s_out[n] = sd / zb;
    }
}

__global__ void __launch_bounds__(BBLK) sa1_bcast(
    const float* __restrict__ s, float* __restrict__ out)
{
    const int n = blockIdx.x;
    const float sv = s[n];
    const f32x4 o = { sv, sv, sv, sv };
    float* op = out + (size_t)n * NPLANE;
#pragma unroll
    for (int i = 0; i < BIT; ++i)
        __builtin_nontemporal_store(
            o, (f32x4*)(op + 4 * (size_t)(i * BBLK + threadIdx.x)));
}

extern "C" void kernel_launch(void* const* d_in, const int* in_sizes, int n_in,
                              void* d_out, int out_size, void* d_ws, size_t ws_size,
                              hipStream_t stream) {
    const float* x     = (const float*)d_in[0];
    const float* fcw_w = (const float*)d_in[1];
    // d_in[2] = fcw_b: softmax-shift-invariant, unused
    const float* fch_w = (const float*)d_in[3];
    // d_in[4] = fch_b: softmax-shift-invariant, unused
    float* out = (float*)d_out;

    const size_t cntBytes = (size_t)NPL * sizeof(unsigned int);          // 8 KB
    const size_t need = cntBytes + (size_t)(2 * NPL) * WSSTR * sizeof(float);  // ~2.7 MB

    if (ws_size >= need) {
        unsigned int* cnt = (unsigned int*)d_ws;
        float* wsp = (float*)((char*)d_ws + cntBytes);
        hipMemsetAsync(d_ws, 0, cntBytes, stream);  // zero per-plane counters
        sa1_fused<<<2 * NPL, BLOCK, 0, stream>>>(x, fcw_w, fch_w, cnt, wsp, out);
    } else {
        float* svec = (float*)d_ws;  // 8 KB
        sa1_reduce<<<NPL, BLOCK, 0, stream>>>(x, fcw_w, fch_w, svec);
        sa1_bcast<<<NPL, BBLK, 0, stream>>>(svec, out);
    }
}

// Round 10
// 343.161 us; speedup vs baseline: 2.1249x; 2.1249x over previous
//
#include <hip/hip_runtime.h>

// Problem: B=8, C=256, H=W=160. n = B*C = 2048 planes.
// Per plane: l[h]=x[h,:]·fcw_w ; alpha=softmax_h(l) ; row[w]=sum_h alpha[h]x[h,w]
//            beta=softmax_w(row*sum(fch_w)) ; s=sum_w beta[w]row[w] ; out[:,:]=s
// Biases are softmax-shift-invariant -> ignored.
//
// v10 = v8 with split depth 2 -> 4 (one variable). 4 blocks per plane,
// 40 rows each (8192 blocks). x-in-registers drops to 5 float4 (20 VGPR)
// -> launch_bounds(320,8) caps VGPR at 64 -> 6 blocks/CU (30/32 wave
// slots), 32 generations/CU -> smoother load/tail interleave than v8's 5
// blocks/CU. Exact 4-way flash-softmax merge in the bcast kernel.
// v9's device-fence fusion REVERTED: per-block AGENT release/acquire
// compiles to buffer_wbl2/buffer_inv (per-XCD L2 writeback) -> 5.5x
// regression, 700 GB/s. Cross-block coherence is off the table.
// Proven keepers: x touched once (nt loads), nt broadcast stores,
// two-kernel split, 4-barrier tail.

#define HH 160
#define WW 160
#define NPLANE (HH * WW)
#define BLOCK 320
#define QN 40     // float4 columns per row
#define PSTR 41   // pad: conflict-light LDS partial gather

// -- split kernel geometry --
#define QTR 40    // rows per partial block
#define RPTQ 5    // rows per v-group (QTR / 8)
#define NREC 4    // partial records per plane
#define WSSTR 164 // floats per ws record: rowacc[160], m, Z, pad2
#define NPL 2048  // planes

typedef float f32x4 __attribute__((ext_vector_type(4)));

// ================= v10 partial-reduce: one quarter-plane per block ========
__global__ void __launch_bounds__(BLOCK, 8) sa1_part(
    const float* __restrict__ x,
    const float* __restrict__ fcw_w,
    float* __restrict__ ws)
{
    const int bid = blockIdx.x;
    const int n = bid >> 2;
    const int g = bid & 3;
    const int t = threadIdx.x;
    const int q = t % QN;
    const int v = t / QN;

    __shared__ float pbuf[QTR * PSTR];   // dot partials; later row partials [8][160]
    __shared__ float larr[QTR];          // l[h] for my 40 rows
    __shared__ float sc[2];              // m_part, Z_part

    const float* xp = x + (size_t)n * NPLANE + (size_t)g * QTR * WW;

    const float4 ww = *(const float4*)(fcw_w + 4 * q);

    // ---- P1: load my 5 float4 (coalesced nt) + dot partials ----
    f32x4 xr[RPTQ];
#pragma unroll
    for (int r = 0; r < RPTQ; ++r)
        xr[r] = __builtin_nontemporal_load(
            (const f32x4*)(xp + (size_t)(v * RPTQ + r) * WW + 4 * q));
#pragma unroll
    for (int r = 0; r < RPTQ; ++r) {
        float p = xr[r].x * ww.x + xr[r].y * ww.y + xr[r].z * ww.z + xr[r].w * ww.w;
        pbuf[(v * RPTQ + r) * PSTR + q] = p;
    }
    __syncthreads();  // B1

    // ---- P2: l[h], 8 threads per row (40 rows x 8 segs of 5) + 3-level shfl ----
    {
        const int row = t >> 3;          // [0,40)
        const int seg = t & 7;           // [0,8)
        const float* pr = pbuf + row * PSTR + seg * 5;
        float hs = ((pr[0] + pr[1]) + (pr[2] + pr[3])) + pr[4];
        hs += __shfl_xor(hs, 1, 64);
        hs += __shfl_xor(hs, 2, 64);
        hs += __shfl_xor(hs, 4, 64);
        if (seg == 0) larr[row] = hs;
    }
    __syncthreads();  // B2

    // ---- P3: wave0 computes m_part, Z_part over 40 logits ----
    if (t < 32) {
        const float l0 = larr[t];
        const float l1 = (t < 8) ? larr[t + 32] : -3.0e38f;
        float m = fmaxf(l0, l1);
#pragma unroll
        for (int off = 16; off >= 1; off >>= 1)
            m = fmaxf(m, __shfl_down(m, off, 32));
        m = __shfl(m, 0, 32);
        float z = __expf(l0 - m) + __expf(l1 - m);  // l1 path underflows to 0
#pragma unroll
        for (int off = 16; off >= 1; off >>= 1)
            z += __shfl_down(z, off, 32);
        if (t == 0) { sc[0] = m; sc[1] = z; }
    }
    __syncthreads();  // B3

    // ---- P4: weighted row partials, exp inline (x still in registers) ----
    const float m = sc[0];
    float4 rp = make_float4(0.f, 0.f, 0.f, 0.f);
#pragma unroll
    for (int r = 0; r < RPTQ; ++r) {
        const float a = __expf(larr[v * RPTQ + r] - m);  // LDS broadcast
        rp.x += a * xr[r].x; rp.y += a * xr[r].y;
        rp.z += a * xr[r].z; rp.w += a * xr[r].w;
    }
    // pbuf dead since B2; write row partials [8][160] (needs 1280 <= 1640)
    *(float4*)(pbuf + v * WW + 4 * q) = rp;
    __syncthreads();  // B4

    // ---- P5: reduce over v, emit ws record {rowacc[160], m, Z} ----
    float* wsr = ws + (size_t)bid * WSSTR;
    if (t < WW) {
        float rs = 0.f;
#pragma unroll
        for (int vv = 0; vv < 8; ++vv) rs += pbuf[vv * WW + t];  // bank=t%32: clean
        wsr[t] = rs;                     // unnormalized; merge handles Z
    }
    if (t == 0) { wsr[160] = sc[0]; wsr[161] = sc[1]; }
}

// ====== v10 merge + broadcast: wave0 merges 4 partials -> s; all store ====
#define BBLK 256
#define BIT (NPLANE / 4 / BBLK)  // 25 float4 iterations per thread

__global__ void __launch_bounds__(BBLK) sa1_bcast_merge(
    const float* __restrict__ ws,
    const float* __restrict__ fch_w,
    float* __restrict__ out)
{
    const int n = blockIdx.x;
    const int t = threadIdx.x;
    __shared__ float sc[2];  // S, s

    float rv[5];
    if (t < 32) {
        const float* r0 = ws + (size_t)(NREC * n) * WSSTR;
        const float* r1 = r0 + WSSTR;
        const float* r2 = r1 + WSSTR;
        const float* r3 = r2 + WSSTR;
        const float m0 = r0[160], z0 = r0[161];
        const float m1 = r1[160], z1 = r1[161];
        const float m2 = r2[160], z2 = r2[161];
        const float m3 = r3[160], z3 = r3[161];
        const float mm = fmaxf(fmaxf(m0, m1), fmaxf(m2, m3));
        const float f0 = __expf(m0 - mm);
        const float f1 = __expf(m1 - mm);
        const float f2 = __expf(m2 - mm);
        const float f3 = __expf(m3 - mm);
        const float rcpZ = 1.0f / (f0 * z0 + f1 * z1 + f2 * z2 + f3 * z3);
#pragma unroll
        for (int j = 0; j < 5; ++j) {
            const int w = t + 32 * j;
            rv[j] = (f0 * r0[w] + f1 * r1[w] + f2 * r2[w] + f3 * r3[w]) * rcpZ;
        }
    } else if (t >= 64 && t < 96) {
        const int u = t - 64;
        float s = 0.f;
#pragma unroll
        for (int j = 0; j < 5; ++j) s += fch_w[u + 32 * j];
#pragma unroll
        for (int off = 16; off >= 1; off >>= 1)
            s += __shfl_down(s, off, 32);
        if (u == 0) sc[0] = s;
    }
    __syncthreads();

    if (t < 32) {
        const float S = sc[0];
        float bl[5];
#pragma unroll
        for (int j = 0; j < 5; ++j) bl[j] = rv[j] * S;
        float mb = bl[0];
#pragma unroll
        for (int j = 1; j < 5; ++j) mb = fmaxf(mb, bl[j]);
#pragma unroll
        for (int off = 16; off >= 1; off >>= 1)
            mb = fmaxf(mb, __shfl_down(mb, off, 32));
        mb = __shfl(mb, 0, 32);
        float zb = 0.f, sd = 0.f;
#pragma unroll
        for (int j = 0; j < 5; ++j) {
            float e = __expf(bl[j] - mb);
            zb += e; sd += e * rv[j];
        }
#pragma unroll
        for (int off = 16; off >= 1; off >>= 1) {
            zb += __shfl_down(zb, off, 32);
            sd += __shfl_down(sd, off, 32);
        }
        if (t == 0) sc[1] = sd / zb;
    }
    __syncthreads();

    const float sv = sc[1];
    const f32x4 o = { sv, sv, sv, sv };
    float* op = out + (size_t)n * NPLANE;
#pragma unroll
    for (int i = 0; i < BIT; ++i)
        __builtin_nontemporal_store(
            o, (f32x4*)(op + 4 * (size_t)(i * BBLK + threadIdx.x)));
}

// ================= fallback (v7 path) if workspace is too small ===========
#define RPT 20

__global__ void __launch_bounds__(BLOCK, 4) sa1_reduce(
    const float* __restrict__ x,
    const float* __restrict__ fcw_w,
    const float* __restrict__ fch_w,
    float* __restrict__ s_out)
{
    const int n = blockIdx.x;
    const int t = threadIdx.x;
    const int q = t % QN;
    const int v = t / QN;

    __shared__ float pbuf[HH * PSTR];
    __shared__ float larrA[HH];
    __shared__ float larrB[HH];
    __shared__ float sc[4];

    const float* xp = x + (size_t)n * NPLANE;
    const float4 ww = *(const float4*)(fcw_w + 4 * q);

    f32x4 xr[RPT];
#pragma unroll
    for (int r = 0; r < RPT; ++r)
        xr[r] = __builtin_nontemporal_load(
            (const f32x4*)(xp + (size_t)(v * RPT + r) * WW + 4 * q));
#pragma unroll
    for (int r = 0; r < RPT; ++r) {
        float p = xr[r].x * ww.x + xr[r].y * ww.y + xr[r].z * ww.z + xr[r].w * ww.w;
        pbuf[(v * RPT + r) * PSTR + q] = p;
    }
    __syncthreads();

    {
        const int h = (t < HH) ? t : (t - HH);
        const int qb = (t < HH) ? 0 : (QN / 2);
        const float* pr = pbuf + h * PSTR + qb;
        float s0 = 0.f, s1 = 0.f, s2 = 0.f, s3 = 0.f;
#pragma unroll
        for (int qq = 0; qq < QN / 2; qq += 4) {
            s0 += pr[qq]; s1 += pr[qq + 1]; s2 += pr[qq + 2]; s3 += pr[qq + 3];
        }
        float hs = (s0 + s1) + (s2 + s3);
        if (t < HH) larrA[h] = hs; else larrB[h] = hs;
    }
    __syncthreads();

    if (t < 32) {
        float lv[5];
#pragma unroll
        for (int j = 0; j < 5; ++j) lv[j] = larrA[t + 32 * j] + larrB[t + 32 * j];
        float m = lv[0];
#pragma unroll
        for (int j = 1; j < 5; ++j) m = fmaxf(m, lv[j]);
#pragma unroll
        for (int off = 16; off >= 1; off >>= 1)
            m = fmaxf(m, __shfl_down(m, off, 32));
        m = __shfl(m, 0, 32);
        float z = 0.f;
#pragma unroll
        for (int j = 0; j < 5; ++j) z += __expf(lv[j] - m);
#pragma unroll
        for (int off = 16; off >= 1; off >>= 1)
            z += __shfl_down(z, off, 32);
        if (t == 0) { sc[0] = m; sc[1] = z; }
    } else if (t >= 64 && t < 96) {
        const int u = t - 64;
        float s = 0.f;
#pragma unroll
        for (int j = 0; j < 5; ++j) s += fch_w[u + 32 * j];
#pragma unroll
        for (int off = 16; off >= 1; off >>= 1)
            s += __shfl_down(s, off, 32);
        if (u == 0) sc[2] = s;
    }
    __syncthreads();

    const float m = sc[0];
    float4 rp = make_float4(0.f, 0.f, 0.f, 0.f);
#pragma unroll
    for (int r = 0; r < RPT; ++r) {
        const int h = v * RPT + r;
        const float a = __expf((larrA[h] + larrB[h]) - m);
        rp.x += a * xr[r].x; rp.y += a * xr[r].y;
        rp.z += a * xr[r].z; rp.w += a * xr[r].w;
    }
    *(float4*)(pbuf + v * WW + 4 * q) = rp;
    __syncthreads();

    if (t < 32) {
        const float S = sc[2];
        const float rcpZ = 1.0f / sc[1];
        float rv[5], bl[5];
#pragma unroll
        for (int j = 0; j < 5; ++j) {
            const int w = t + 32 * j;
            float rs = 0.f;
#pragma unroll
            for (int vv = 0; vv < 8; ++vv) rs += pbuf[vv * WW + w];
            rv[j] = rs * rcpZ;
            bl[j] = rv[j] * S;
        }
        float mb = bl[0];
#pragma unroll
        for (int j = 1; j < 5; ++j) mb = fmaxf(mb, bl[j]);
#pragma unroll
        for (int off = 16; off >= 1; off >>= 1)
            mb = fmaxf(mb, __shfl_down(mb, off, 32));
        mb = __shfl(mb, 0, 32);
        float zb = 0.f, sd = 0.f;
#pragma unroll
        for (int j = 0; j < 5; ++j) {
            float e = __expf(bl[j] - mb);
            zb += e; sd += e * rv[j];
        }
#pragma unroll
        for (int off = 16; off >= 1; off >>= 1) {
            zb += __shfl_down(zb, off, 32);
            sd += __shfl_down(sd, off, 32);
        }
        if (t == 0) s_out[n] = sd / zb;
    }
}

__global__ void __launch_bounds__(BBLK) sa1_bcast(
    const float* __restrict__ s, float* __restrict__ out)
{
    const int n = blockIdx.x;
    const float sv = s[n];
    const f32x4 o = { sv, sv, sv, sv };
    float* op = out + (size_t)n * NPLANE;
#pragma unroll
    for (int i = 0; i < BIT; ++i)
        __builtin_nontemporal_store(
            o, (f32x4*)(op + 4 * (size_t)(i * BBLK + threadIdx.x)));
}

extern "C" void kernel_launch(void* const* d_in, const int* in_sizes, int n_in,
                              void* d_out, int out_size, void* d_ws, size_t ws_size,
                              hipStream_t stream) {
    const float* x     = (const float*)d_in[0];
    const float* fcw_w = (const float*)d_in[1];
    // d_in[2] = fcw_b: softmax-shift-invariant, unused
    const float* fch_w = (const float*)d_in[3];
    // d_in[4] = fch_b: softmax-shift-invariant, unused
    float* out = (float*)d_out;

    const size_t need = (size_t)(NREC * NPL) * WSSTR * sizeof(float);  // ~5.4 MB

    if (ws_size >= need) {
        float* wsp = (float*)d_ws;
        sa1_part<<<NREC * NPL, BLOCK, 0, stream>>>(x, fcw_w, wsp);
        sa1_bcast_merge<<<NPL, BBLK, 0, stream>>>(wsp, fch_w, out);
    } else {
        float* svec = (float*)d_ws;  // 8 KB
        sa1_reduce<<<NPL, BLOCK, 0, stream>>>(x, fcw_w, fch_w, svec);
        sa1_bcast<<<NPL, BBLK, 0, stream>>>(svec, out);
    }
}

// Round 11
// 341.692 us; speedup vs baseline: 2.1340x; 1.0043x over previous
//
#include <hip/hip_runtime.h>

// Problem: B=8, C=256, H=W=160. n = B*C = 2048 planes.
// Per plane: l[h]=x[h,:]·fcw_w ; alpha=softmax_h(l) ; row[w]=sum_h alpha[h]x[h,w]
//            beta=softmax_w(row*sum(fch_w)) ; s=sum_w beta[w]row[w] ; out[:,:]=s
// Biases are softmax-shift-invariant -> ignored.
//
// v11 = v8 EXACTLY (revert of v10). Measured optimum of the family:
//   v4 fused 347.3 | v5-v7 split ~345.3 | v8 split-depth-2 341.2 (BEST)
//   | v9 fence-fused 729 (buffer_wbl2 serialization) | v10 depth-4 343.2.
// Structure: 2 blocks per plane (4096 x 80 rows), exact flash-softmax
// partials {rowacc[160], m, Z} -> ws; bcast kernel merges 2 records,
// computes beta/s, nt-broadcast-stores the plane.
// Proven keepers: x touched exactly once (nt loads; 40 VGPR resident),
// launch_bounds(320,7) -> 5 blocks/CU, nt stores (poison-writeback fix),
// two-kernel split, 4-barrier tail.
// Remaining gap to 420MB/6.5TB/s = 65us ideal is ~15-19us of intrinsic
// read-phase structure + dispatch gap; all measured levers exhausted.

#define HH 160
#define WW 160
#define NPLANE (HH * WW)
#define BLOCK 320
#define QN 40     // float4 columns per row
#define PSTR 41   // pad: conflict-light LDS partial gather

// -- split kernel geometry --
#define HALF 80   // rows per partial block
#define RPTH 10   // rows per v-group (HALF / 8)
#define WSSTR 164 // floats per ws record: rowacc[160], m, Z, pad2

typedef float f32x4 __attribute__((ext_vector_type(4)));

// ================= partial-reduce: one half-plane per block ===============
__global__ void __launch_bounds__(BLOCK, 7) sa1_part(
    const float* __restrict__ x,
    const float* __restrict__ fcw_w,
    float* __restrict__ ws)
{
    const int bid = blockIdx.x;
    const int n = bid >> 1;
    const int g = bid & 1;
    const int t = threadIdx.x;
    const int q = t % QN;
    const int v = t / QN;

    __shared__ float pbuf[HALF * PSTR];  // dot partials; later row partials [8][160]
    __shared__ float larr[HALF];         // l[h] for my 80 rows
    __shared__ float sc[2];              // m_part, Z_part

    const float* xp = x + (size_t)n * NPLANE + (size_t)g * HALF * WW;

    const float4 ww = *(const float4*)(fcw_w + 4 * q);

    // ---- P1: load my 10 float4 (coalesced nt) + dot partials ----
    f32x4 xr[RPTH];
#pragma unroll
    for (int r = 0; r < RPTH; ++r)
        xr[r] = __builtin_nontemporal_load(
            (const f32x4*)(xp + (size_t)(v * RPTH + r) * WW + 4 * q));
#pragma unroll
    for (int r = 0; r < RPTH; ++r) {
        float p = xr[r].x * ww.x + xr[r].y * ww.y + xr[r].z * ww.z + xr[r].w * ww.w;
        pbuf[(v * RPTH + r) * PSTR + q] = p;
    }
    __syncthreads();  // B1

    // ---- P2: l[h], 4 threads per row (80 rows x 4 segs of 10) + 4-lane shfl ----
    {
        const int row = t >> 2;          // [0,80)
        const int seg = t & 3;           // [0,4)
        const float* pr = pbuf + row * PSTR + seg * 10;
        float s0 = 0.f, s1 = 0.f;
#pragma unroll
        for (int i = 0; i < 10; i += 2) { s0 += pr[i]; s1 += pr[i + 1]; }
        float hs = s0 + s1;
        hs += __shfl_xor(hs, 1, 64);
        hs += __shfl_xor(hs, 2, 64);
        if (seg == 0) larr[row] = hs;
    }
    __syncthreads();  // B2

    // ---- P3: wave0 computes m_part, Z_part over 80 logits ----
    if (t < 32) {
        const float l0 = larr[t];
        const float l1 = larr[t + 32];
        const float l2 = (t < 16) ? larr[t + 64] : -3.0e38f;
        float m = fmaxf(l0, fmaxf(l1, l2));
#pragma unroll
        for (int off = 16; off >= 1; off >>= 1)
            m = fmaxf(m, __shfl_down(m, off, 32));
        m = __shfl(m, 0, 32);
        float z = __expf(l0 - m) + __expf(l1 - m) + __expf(l2 - m);  // l2 path underflows to 0
#pragma unroll
        for (int off = 16; off >= 1; off >>= 1)
            z += __shfl_down(z, off, 32);
        if (t == 0) { sc[0] = m; sc[1] = z; }
    }
    __syncthreads();  // B3

    // ---- P4: weighted row partials, exp inline (x still in registers) ----
    const float m = sc[0];
    float4 rp = make_float4(0.f, 0.f, 0.f, 0.f);
#pragma unroll
    for (int r = 0; r < RPTH; ++r) {
        const float a = __expf(larr[v * RPTH + r] - m);  // LDS broadcast
        rp.x += a * xr[r].x; rp.y += a * xr[r].y;
        rp.z += a * xr[r].z; rp.w += a * xr[r].w;
    }
    // pbuf dead since B2; write row partials [8][160]
    *(float4*)(pbuf + v * WW + 4 * q) = rp;
    __syncthreads();  // B4

    // ---- P5: reduce over v, emit ws record {rowacc[160], m, Z} ----
    float* wsr = ws + (size_t)bid * WSSTR;
    if (t < WW) {
        float rs = 0.f;
#pragma unroll
        for (int vv = 0; vv < 8; ++vv) rs += pbuf[vv * WW + t];  // bank=t%32: clean
        wsr[t] = rs;                     // NOT normalized; merge handles Z
    }
    if (t == 0) { wsr[160] = sc[0]; wsr[161] = sc[1]; }
}

// ====== merge + broadcast: wave0 merges 2 partials -> s; all store ========
#define BBLK 256
#define BIT (NPLANE / 4 / BBLK)  // 25 float4 iterations per thread

__global__ void __launch_bounds__(BBLK) sa1_bcast_merge(
    const float* __restrict__ ws,
    const float* __restrict__ fch_w,
    float* __restrict__ out)
{
    const int n = blockIdx.x;
    const int t = threadIdx.x;
    __shared__ float sc[2];  // S, s

    float rv[5];
    if (t < 32) {
        const float* r0 = ws + (size_t)(2 * n) * WSSTR;
        const float* r1 = ws + (size_t)(2 * n + 1) * WSSTR;
        const float m0 = r0[160], z0 = r0[161];
        const float m1 = r1[160], z1 = r1[161];
        const float mm = fmaxf(m0, m1);
        const float f0 = __expf(m0 - mm);
        const float f1 = __expf(m1 - mm);
        const float rcpZ = 1.0f / (f0 * z0 + f1 * z1);
#pragma unroll
        for (int j = 0; j < 5; ++j) {
            const int w = t + 32 * j;
            rv[j] = (f0 * r0[w] + f1 * r1[w]) * rcpZ;  // row[w]
        }
    } else if (t >= 64 && t < 96) {
        const int u = t - 64;
        float s = 0.f;
#pragma unroll
        for (int j = 0; j < 5; ++j) s += fch_w[u + 32 * j];
#pragma unroll
        for (int off = 16; off >= 1; off >>= 1)
            s += __shfl_down(s, off, 32);
        if (u == 0) sc[0] = s;
    }
    __syncthreads();

    if (t < 32) {
        const float S = sc[0];
        float bl[5];
#pragma unroll
        for (int j = 0; j < 5; ++j) bl[j] = rv[j] * S;
        float mb = bl[0];
#pragma unroll
        for (int j = 1; j < 5; ++j) mb = fmaxf(mb, bl[j]);
#pragma unroll
        for (int off = 16; off >= 1; off >>= 1)
            mb = fmaxf(mb, __shfl_down(mb, off, 32));
        mb = __shfl(mb, 0, 32);
        float zb = 0.f, sd = 0.f;
#pragma unroll
        for (int j = 0; j < 5; ++j) {
            float e = __expf(bl[j] - mb);
            zb += e; sd += e * rv[j];
        }
#pragma unroll
        for (int off = 16; off >= 1; off >>= 1) {
            zb += __shfl_down(zb, off, 32);
            sd += __shfl_down(sd, off, 32);
        }
        if (t == 0) sc[1] = sd / zb;
    }
    __syncthreads();

    const float sv = sc[1];
    const f32x4 o = { sv, sv, sv, sv };
    float* op = out + (size_t)n * NPLANE;
#pragma unroll
    for (int i = 0; i < BIT; ++i)
        __builtin_nontemporal_store(
            o, (f32x4*)(op + 4 * (size_t)(i * BBLK + threadIdx.x)));
}

// ================= fallback (v7 path) if workspace is too small ===========
#define RPT 20

__global__ void __launch_bounds__(BLOCK, 4) sa1_reduce(
    const float* __restrict__ x,
    const float* __restrict__ fcw_w,
    const float* __restrict__ fch_w,
    float* __restrict__ s_out)
{
    const int n = blockIdx.x;
    const int t = threadIdx.x;
    const int q = t % QN;
    const int v = t / QN;

    __shared__ float pbuf[HH * PSTR];
    __shared__ float larrA[HH];
    __shared__ float larrB[HH];
    __shared__ float sc[4];

    const float* xp = x + (size_t)n * NPLANE;
    const float4 ww = *(const float4*)(fcw_w + 4 * q);

    f32x4 xr[RPT];
#pragma unroll
    for (int r = 0; r < RPT; ++r)
        xr[r] = __builtin_nontemporal_load(
            (const f32x4*)(xp + (size_t)(v * RPT + r) * WW + 4 * q));
#pragma unroll
    for (int r = 0; r < RPT; ++r) {
        float p = xr[r].x * ww.x + xr[r].y * ww.y + xr[r].z * ww.z + xr[r].w * ww.w;
        pbuf[(v * RPT + r) * PSTR + q] = p;
    }
    __syncthreads();

    {
        const int h = (t < HH) ? t : (t - HH);
        const int qb = (t < HH) ? 0 : (QN / 2);
        const float* pr = pbuf + h * PSTR + qb;
        float s0 = 0.f, s1 = 0.f, s2 = 0.f, s3 = 0.f;
#pragma unroll
        for (int qq = 0; qq < QN / 2; qq += 4) {
            s0 += pr[qq]; s1 += pr[qq + 1]; s2 += pr[qq + 2]; s3 += pr[qq + 3];
        }
        float hs = (s0 + s1) + (s2 + s3);
        if (t < HH) larrA[h] = hs; else larrB[h] = hs;
    }
    __syncthreads();

    if (t < 32) {
        float lv[5];
#pragma unroll
        for (int j = 0; j < 5; ++j) lv[j] = larrA[t + 32 * j] + larrB[t + 32 * j];
        float m = lv[0];
#pragma unroll
        for (int j = 1; j < 5; ++j) m = fmaxf(m, lv[j]);
#pragma unroll
        for (int off = 16; off >= 1; off >>= 1)
            m = fmaxf(m, __shfl_down(m, off, 32));
        m = __shfl(m, 0, 32);
        float z = 0.f;
#pragma unroll
        for (int j = 0; j < 5; ++j) z += __expf(lv[j] - m);
#pragma unroll
        for (int off = 16; off >= 1; off >>= 1)
            z += __shfl_down(z, off, 32);
        if (t == 0) { sc[0] = m; sc[1] = z; }
    } else if (t >= 64 && t < 96) {
        const int u = t - 64;
        float s = 0.f;
#pragma unroll
        for (int j = 0; j < 5; ++j) s += fch_w[u + 32 * j];
#pragma unroll
        for (int off = 16; off >= 1; off >>= 1)
            s += __shfl_down(s, off, 32);
        if (u == 0) sc[2] = s;
    }
    __syncthreads();

    const float m = sc[0];
    float4 rp = make_float4(0.f, 0.f, 0.f, 0.f);
#pragma unroll
    for (int r = 0; r < RPT; ++r) {
        const int h = v * RPT + r;
        const float a = __expf((larrA[h] + larrB[h]) - m);
        rp.x += a * xr[r].x; rp.y += a * xr[r].y;
        rp.z += a * xr[r].z; rp.w += a * xr[r].w;
    }
    *(float4*)(pbuf + v * WW + 4 * q) = rp;
    __syncthreads();

    if (t < 32) {
        const float S = sc[2];
        const float rcpZ = 1.0f / sc[1];
        float rv[5], bl[5];
#pragma unroll
        for (int j = 0; j < 5; ++j) {
            const int w = t + 32 * j;
            float rs = 0.f;
#pragma unroll
            for (int vv = 0; vv < 8; ++vv) rs += pbuf[vv * WW + w];
            rv[j] = rs * rcpZ;
            bl[j] = rv[j] * S;
        }
        float mb = bl[0];
#pragma unroll
        for (int j = 1; j < 5; ++j) mb = fmaxf(mb, bl[j]);
#pragma unroll
        for (int off = 16; off >= 1; off >>= 1)
            mb = fmaxf(mb, __shfl_down(mb, off, 32));
        mb = __shfl(mb, 0, 32);
        float zb = 0.f, sd = 0.f;
#pragma unroll
        for (int j = 0; j < 5; ++j) {
            float e = __expf(bl[j] - mb);
            zb += e; sd += e * rv[j];
        }
#pragma unroll
        for (int off = 16; off >= 1; off >>= 1) {
            zb += __shfl_down(zb, off, 32);
            sd += __shfl_down(sd, off, 32);
        }
        if (t == 0) s_out[n] = sd / zb;
    }
}

__global__ void __launch_bounds__(BBLK) sa1_bcast(
    const float* __restrict__ s, float* __restrict__ out)
{
    const int n = blockIdx.x;
    const float sv = s[n];
    const f32x4 o = { sv, sv, sv, sv };
    float* op = out + (size_t)n * NPLANE;
#pragma unroll
    for (int i = 0; i < BIT; ++i)
        __builtin_nontemporal_store(
            o, (f32x4*)(op + 4 * (size_t)(i * BBLK + threadIdx.x)));
}

extern "C" void kernel_launch(void* const* d_in, const int* in_sizes, int n_in,
                              void* d_out, int out_size, void* d_ws, size_t ws_size,
                              hipStream_t stream) {
    const float* x     = (const float*)d_in[0];
    const float* fcw_w = (const float*)d_in[1];
    // d_in[2] = fcw_b: softmax-shift-invariant, unused
    const float* fch_w = (const float*)d_in[3];
    // d_in[4] = fch_b: softmax-shift-invariant, unused
    float* out = (float*)d_out;

    const int nplanes = 8 * 256;  // B*C
    const size_t need = (size_t)(2 * nplanes) * WSSTR * sizeof(float);  // 2.7 MB

    if (ws_size >= need) {
        float* wsp = (float*)d_ws;
        sa1_part<<<2 * nplanes, BLOCK, 0, stream>>>(x, fcw_w, wsp);
        sa1_bcast_merge<<<nplanes, BBLK, 0, stream>>>(wsp, fch_w, out);
    } else {
        float* svec = (float*)d_ws;  // 8 KB
        sa1_reduce<<<nplanes, BLOCK, 0, stream>>>(x, fcw_w, fch_w, svec);
        sa1_bcast<<<nplanes, BBLK, 0, stream>>>(svec, out);
    }
}